// Round 6
// baseline (2145.665 us; speedup 1.0000x reference)
//
#include <hip/hip_runtime.h>
#include <math.h>

#define H      128
#define NPATH  8192
#define TLEN   512
#define BP     32            // paths per block
#define NTHR   512           // 8 waves: (wp 0..3) x (nt 0..1)

typedef short bf16x8 __attribute__((ext_vector_type(8)));
typedef float f32x4  __attribute__((ext_vector_type(4)));

#define MFMA(a,b,c) __builtin_amdgcn_mfma_f32_16x16x32_bf16((a),(b),(c),0,0,0)

// Block-wide barrier that drains ONLY LDS (lgkm). Cross-wave dataflow in this
// kernel is LDS-only; private global loads/stores (dW prefetch, out store)
// must NOT be drained here -- __syncthreads() would emit vmcnt(0) and stall
// ~300-900 cyc per barrier on in-flight HBM/L3 ops, 4x per step.
#define BAR() asm volatile("s_waitcnt lgkmcnt(0)\n\ts_barrier" ::: "memory")

// ---- LDS byte offsets ----
// Weight A-frag buffers: chunk-tiled [c = col>>3][row 0..127] x 16B
#define O_WF2T  0                    // fwd-f A (fw2^T): row=out n, col=in k
#define O_WG2T  32768                // fwd-g A (gw2^T)
#define O_WG2R  65536                // bwd   A (gw2):   row=in k, col=out n
// Activation B buffers: chunk-tiled [c = k>>3][path 0..31] x 16B
#define O_BFH   98304                // h1f hi (reused c2 hi)
#define O_BFL   106496               // h1f lo (reused c2 lo)
#define O_BGH   114688               // h1g hi
#define O_BGL   122880               // h1g lo
#define O_PF    131072               // f partials [4 wp][32 path] float2
#define O_PRAW  132096
#define O_PCORR 133120
#define O_EP    134144               // epilogue invariants, f32 arrays [128]
#define EP_FB2   0
#define EP_GB2   512
#define EP_W3F0  1024
#define EP_W3F1  1536
#define EP_W3G0  2048
#define EP_W3G1  2560
#define EP_GW1B0 3072
#define EP_GW1B1 3584
#define EP_GB1B  4096
#define O_TS    138752               // ts [512] fp32
#define SMEM_BYTES (O_TS + TLEN*4)   // 140800 B < 160 KiB

__device__ __forceinline__ float bf2f(unsigned v){ return __uint_as_float(v << 16); }
__device__ __forceinline__ unsigned short f2bf(float f){
  unsigned u = __float_as_uint(f);
  return (unsigned short)((u + 0x7fffu + ((u >> 16) & 1u)) >> 16);
}
__device__ __forceinline__ float ldany(const void* p, long long i, bool isbf){
  return isbf ? bf2f(((const unsigned short*)p)[i]) : ((const float*)p)[i];
}
__device__ __forceinline__ unsigned short ldbf(const void* p, long long i, bool isbf){
  return isbf ? ((const unsigned short*)p)[i] : f2bf(((const float*)p)[i]);
}
__device__ __forceinline__ float fsig(float x){
  return __builtin_amdgcn_rcpf(1.0f + __expf(-x));
}
__device__ __forceinline__ float fsilu(float x){ return x * fsig(x); }
__device__ __forceinline__ float fsilud(float x){
  float s = fsig(x); return s * (1.0f + x * (1.0f - s));
}
__device__ __forceinline__ float fsoftplus(float x){
  if (x > 15.0f) return x;
  return __logf(1.0f + __expf(x));
}
// packed RTNE f32->2xbf16 (lo16 = a, hi16 = b)  [validated rounds 2-5]
__device__ __forceinline__ unsigned cvtpk(float a, float b){
  unsigned r; asm("v_cvt_pk_bf16_f32 %0, %1, %2" : "=v"(r) : "v"(a), "v"(b)); return r;
}
__device__ __forceinline__ bf16x8 asfrag(uint4 u){
  union { uint4 u; bf16x8 b; } v; v.u = u; return v.b;
}

__global__ __launch_bounds__(NTHR, 2)
void GeneratorSDE_kernel(const void* __restrict__ y0, const void* __restrict__ ts,
                         const void* __restrict__ dW,
                         const void* __restrict__ fw1, const void* __restrict__ fb1,
                         const void* __restrict__ fw2, const void* __restrict__ fb2,
                         const void* __restrict__ fw3, const void* __restrict__ fb3,
                         const void* __restrict__ gw1, const void* __restrict__ gb1,
                         const void* __restrict__ gw2, const void* __restrict__ gb2,
                         const void* __restrict__ gw3, const void* __restrict__ gb3,
                         void* __restrict__ out)
{
  extern __shared__ char sm[];
  const int tid  = threadIdx.x;
  const int lane = tid & 63;
  const int w    = tid >> 6;       // wave 0..7
  const int wp   = w >> 1;         // M-pair index 0..3 (rows 32*wp..32*wp+31)
  const int nt   = w & 1;          // half (paths nt*16..nt*16+15)
  const int m16  = lane & 15;
  const int q    = lane >> 4;      // 0..3
  const int gpb  = blockIdx.x * BP;
  const int p1   = nt*16 + m16;    // this lane's path (block-local)
  const int gp   = gpb + p1;
  const int k8   = wp*32 + q*8;    // S0 k-slice (8 neurons)

  const bool isbf = (((const unsigned*)ts)[1] != 0x3f800000u);

  // ---------- loop-invariant LDS base addresses (bytes) ----------
  const int RACT  = O_BFH + ((q*32 + p1) << 4);
  const int WACT  = O_BFH + (((wp*4 + q)*32 + p1) << 4);
  const int WC2   = O_BFH + (((wp*4 + (q >> 1))*32 + p1) << 4) + ((q & 1) << 3);
  const int RAW   = O_WF2T + ((q*128 + wp*32 + m16) << 4);
  const int RAR   = O_WG2R + ((q*128 + wp*32 + m16) << 4);
  const int RPART = O_PF + (p1 << 3);
  const int WPART = O_PF + ((wp*32 + p1) << 3);
  const int REP   = O_EP + wp*128 + q*16;

  // ---------- stage weights into LDS (chunk-tiled) ----------
  for (int e = tid; e < H * H; e += NTHR){
    int k = e >> 7, n = e & 127;   // fw2/gw2 element [k_in][n_out]
    unsigned short fv = ldbf(fw2, e, isbf);
    unsigned short gv = ldbf(gw2, e, isbf);
    *(unsigned short*)(sm + O_WF2T + (((k >> 3)*128 + n) << 4) + ((k & 7) << 1)) = fv;
    *(unsigned short*)(sm + O_WG2T + (((k >> 3)*128 + n) << 4) + ((k & 7) << 1)) = gv;
    *(unsigned short*)(sm + O_WG2R + (((n >> 3)*128 + k) << 4) + ((n & 7) << 1)) = gv;
  }
  // epilogue invariants -> LDS (broadcast-read later)
  if (tid < H){
    int e = tid;
    ((float*)(sm + O_EP + EP_FB2))[e]   = ldany(fb2, e, isbf);
    ((float*)(sm + O_EP + EP_GB2))[e]   = ldany(gb2, e, isbf);
    ((float*)(sm + O_EP + EP_W3F0))[e]  = ldany(fw3, 2*e + 0, isbf);
    ((float*)(sm + O_EP + EP_W3F1))[e]  = ldany(fw3, 2*e + 1, isbf);
    ((float*)(sm + O_EP + EP_W3G0))[e]  = ldany(gw3, 2*e + 0, isbf);
    ((float*)(sm + O_EP + EP_W3G1))[e]  = ldany(gw3, 2*e + 1, isbf);
    ((float*)(sm + O_EP + EP_GW1B0))[e] = ldany(gw1, e, isbf);
    ((float*)(sm + O_EP + EP_GW1B1))[e] = ldany(gw1, H + e, isbf);
    ((float*)(sm + O_EP + EP_GB1B))[e]  = ldany(gb1, e, isbf);
  }
  for (int e = tid; e < TLEN; e += NTHR)
    ((float*)(sm + O_TS))[e] = ldany(ts, e, isbf);

  // ---------- register invariants: S0 layer-1 slices only ----------
  // spread column folded: y0*w0 + y1*w1 + (y0-y1)*w2 = y0*(w0+w2) + y1*(w1-w2)
  float fw1a[8], fw1b[8], fb1r[8], gw1r0[8], gw1r1[8], gb1r[8];
  #pragma unroll
  for (int kk = 0; kk < 8; ++kk){
    int k = k8 + kk;
    float r0 = ldany(fw1, k, isbf), r1 = ldany(fw1, H + k, isbf), r2 = ldany(fw1, 2*H + k, isbf);
    fw1a[kk]  = r0 + r2;
    fw1b[kk]  = r1 - r2;
    fb1r[kk]  = ldany(fb1, k,     isbf);
    gw1r0[kk] = ldany(gw1, k,     isbf);
    gw1r1[kk] = ldany(gw1, H + k, isbf);
    gb1r[kk]  = ldany(gb1, k,     isbf);
  }
  const float fb3r0 = ldany(fb3, 0, isbf), fb3r1 = ldany(fb3, 1, isbf);
  const float gb3r0 = ldany(gb3, 0, isbf), gb3r1 = ldany(gb3, 1, isbf);

  // ---------- y in registers (redundant across the 16 lanes sharing a path) ----------
  float ycur0 = ldany(y0, (long long)gp*2 + 0, isbf);
  float ycur1 = ldany(y0, (long long)gp*2 + 1, isbf);
  if (w < 2 && lane < 16){                       // one store per path
    size_t r = (size_t)gp * TLEN;
    if (isbf) ((unsigned*)out)[r] = (unsigned)f2bf(ycur0) | ((unsigned)f2bf(ycur1) << 16);
    else      ((float2*)out)[r]   = make_float2(ycur0, ycur1);
  }
  float2 dwcur;
  {
    long long e = (long long)gp * 2;             // t = 0
    if (isbf){ unsigned u = *(const unsigned*)((const unsigned short*)dW + e);
               dwcur = make_float2(bf2f(u & 0xffffu), bf2f(u >> 16)); }
    else       dwcur = *(const float2*)((const float*)dW + e);
  }
  __syncthreads();                               // staging visible (full drain, once)

  const float* TSf = (const float*)(sm + O_TS);

  for (int t = 0; t < TLEN - 1; ++t){
    float dt = TSf[t+1] - TSf[t];
    float sqdt = sqrtf(dt);

    // prefetch next-step dW for this lane's path (stays in flight across BAR()s)
    float2 dwnext;
    {
      int tn = (t + 1 <= TLEN - 2) ? t + 1 : TLEN - 2;
      long long e = ((long long)tn * NPATH + gp) * 2;
      if (isbf){ unsigned u = *(const unsigned*)((const unsigned short*)dW + e);
                 dwnext = make_float2(bf2f(u & 0xffffu), bf2f(u >> 16)); }
      else       dwnext = *(const float2*)((const float*)dW + e);
    }

    // ---- S0: layer 1 (drift + diffusion) for (path p1, 8 k's), split hi/lo ----
    {
      float hf[8], hg[8];
      #pragma unroll
      for (int kk = 0; kk < 8; ++kk){
        hf[kk] = fsilu(fb1r[kk] + ycur0*fw1a[kk]  + ycur1*fw1b[kk]);
        hg[kk] = fsilu(gb1r[kk] + ycur0*gw1r0[kk] + ycur1*gw1r1[kk]);
      }
      unsigned fh[4], fl[4], gh[4], gl[4];
      #pragma unroll
      for (int i = 0; i < 4; ++i){
        fh[i] = cvtpk(hf[2*i], hf[2*i+1]);
        gh[i] = cvtpk(hg[2*i], hg[2*i+1]);
        float f0 = __uint_as_float(fh[i] << 16), f1 = __uint_as_float(fh[i] & 0xffff0000u);
        float g0 = __uint_as_float(gh[i] << 16), g1 = __uint_as_float(gh[i] & 0xffff0000u);
        fl[i] = cvtpk(hf[2*i] - f0, hf[2*i+1] - f1);
        gl[i] = cvtpk(hg[2*i] - g0, hg[2*i+1] - g1);
      }
      *(uint4*)(sm + WACT        ) = make_uint4(fh[0], fh[1], fh[2], fh[3]);
      *(uint4*)(sm + WACT +  8192) = make_uint4(fl[0], fl[1], fl[2], fl[3]);
      *(uint4*)(sm + WACT + 16384) = make_uint4(gh[0], gh[1], gh[2], gh[3]);
      *(uint4*)(sm + WACT + 24576) = make_uint4(gl[0], gl[1], gl[2], gl[3]);
    }
    BAR();                                               // A: acts ready (LDS-only)

    // ---- S1: fwd MFMAs (f and g) + head partials ----
    f32x4 accg[2];
    float sgr[8];
    f32x4 w3g0v[2], w3g1v[2];
    {
      f32x4 accf[2];
      accf[0] = (f32x4)0.f; accf[1] = (f32x4)0.f;
      accg[0] = (f32x4)0.f; accg[1] = (f32x4)0.f;
      #pragma unroll
      for (int kt = 0; kt < 4; ++kt){
        bf16x8 bfh = asfrag(*(const uint4*)(sm + RACT + kt*2048        ));
        bf16x8 bfl = asfrag(*(const uint4*)(sm + RACT + kt*2048 +  8192));
        bf16x8 bgh = asfrag(*(const uint4*)(sm + RACT + kt*2048 + 16384));
        bf16x8 bgl = asfrag(*(const uint4*)(sm + RACT + kt*2048 + 24576));
        bf16x8 af0 = asfrag(*(const uint4*)(sm + RAW + kt*8192        ));
        bf16x8 af1 = asfrag(*(const uint4*)(sm + RAW + kt*8192 +   256));
        bf16x8 ag0 = asfrag(*(const uint4*)(sm + RAW + kt*8192 + 32768));
        bf16x8 ag1 = asfrag(*(const uint4*)(sm + RAW + kt*8192 + 33024));
        accf[0] = MFMA(af0, bfl, accf[0]); accf[0] = MFMA(af0, bfh, accf[0]);
        accf[1] = MFMA(af1, bfl, accf[1]); accf[1] = MFMA(af1, bfh, accf[1]);
        accg[0] = MFMA(ag0, bgl, accg[0]); accg[0] = MFMA(ag0, bgh, accg[0]);
        accg[1] = MFMA(ag1, bgl, accg[1]); accg[1] = MFMA(ag1, bgh, accg[1]);
      }
      float pf0 = 0, pf1 = 0, pr0 = 0, pr1 = 0;
      #pragma unroll
      for (int mi = 0; mi < 2; ++mi){
        f32x4 fb2v  = *(const f32x4*)(sm + REP + mi*64 + EP_FB2);
        f32x4 gb2v  = *(const f32x4*)(sm + REP + mi*64 + EP_GB2);
        f32x4 w3f0v = *(const f32x4*)(sm + REP + mi*64 + EP_W3F0);
        f32x4 w3f1v = *(const f32x4*)(sm + REP + mi*64 + EP_W3F1);
        w3g0v[mi] = *(const f32x4*)(sm + REP + mi*64 + EP_W3G0);
        w3g1v[mi] = *(const f32x4*)(sm + REP + mi*64 + EP_W3G1);
        #pragma unroll
        for (int r = 0; r < 4; ++r){
          float vf = fsilu(accf[mi][r] + fb2v[r]);
          pf0 += vf * w3f0v[r];
          pf1 += vf * w3f1v[r];
          float zg = accg[mi][r] + gb2v[r];
          float s  = fsig(zg);
          accg[mi][r] = zg;                    // keep biased z2g for S3
          sgr[mi*4+r] = s;                     // keep sigmoid for silu'
          float vg = zg * s;
          pr0 += vg * w3g0v[mi][r];
          pr1 += vg * w3g1v[mi][r];
        }
      }
      pf0 += __shfl_xor(pf0, 16, 64); pf0 += __shfl_xor(pf0, 32, 64);
      pf1 += __shfl_xor(pf1, 16, 64); pf1 += __shfl_xor(pf1, 32, 64);
      pr0 += __shfl_xor(pr0, 16, 64); pr0 += __shfl_xor(pr0, 32, 64);
      pr1 += __shfl_xor(pr1, 16, 64); pr1 += __shfl_xor(pr1, 32, 64);
      if (lane < 16){
        *(float2*)(sm + WPART       ) = make_float2(pf0, pf1);
        *(float2*)(sm + WPART + 1024) = make_float2(pr0, pr1);
      }
    }
    BAR();                                               // B: partials ready

    // ---- S2': every lane combines raw for ITS path -> g, cr (registers) ----
    float g0, g1, dw0, dw1, cr0, cr1;
    {
      float raw0 = gb3r0, raw1 = gb3r1;
      #pragma unroll
      for (int w2 = 0; w2 < 4; ++w2){
        float2 v = *(const float2*)(sm + RPART + w2*256 + 1024);
        raw0 += v.x; raw1 += v.y;
      }
      dw0 = dwcur.x * sqdt; dw1 = dwcur.y * sqdt;
      float vv0 = 0.5f*(dw0*dw0 - dt), vv1 = 0.5f*(dw1*dw1 - dt);
      float sp0 = fsoftplus(raw0), sp1 = fsoftplus(raw1);
      g0 = fminf(fmaxf(sp0, 1e-4f), 5.0f);
      g1 = fminf(fmaxf(sp1, 1e-4f), 5.0f);
      float m0 = (sp0 > 1e-4f && sp0 < 5.0f) ? 1.0f : 0.0f;
      float m1 = (sp1 > 1e-4f && sp1 < 5.0f) ? 1.0f : 0.0f;
      cr0 = vv0 * (g0 * fsig(raw0) * m0);
      cr1 = vv1 * (g1 * fsig(raw1) * m1);
    }

    // ---- S3: cotangent seed c2 -> BFH/BFL (reuse), silu' from kept sigmoid ----
    #pragma unroll
    for (int mi = 0; mi < 2; ++mi){
      float c2[4];
      #pragma unroll
      for (int r = 0; r < 4; ++r){
        float s = sgr[mi*4+r], z = accg[mi][r];
        float sd = s * (1.0f + z * (1.0f - s));
        c2[r] = (cr0 * w3g0v[mi][r] + cr1 * w3g1v[mi][r]) * sd;
      }
      unsigned h0 = cvtpk(c2[0], c2[1]), h1 = cvtpk(c2[2], c2[3]);
      float a0 = __uint_as_float(h0 << 16), a1 = __uint_as_float(h0 & 0xffff0000u);
      float a2 = __uint_as_float(h1 << 16), a3 = __uint_as_float(h1 & 0xffff0000u);
      unsigned l0 = cvtpk(c2[0] - a0, c2[1] - a1), l1 = cvtpk(c2[2] - a2, c2[3] - a3);
      *(uint2*)(sm + WC2 + mi*1024       ) = make_uint2(h0, h1);
      *(uint2*)(sm + WC2 + mi*1024 + 8192) = make_uint2(l0, l1);
    }
    BAR();                                               // D: c2 ready

    // ---- S4: backward MFMA (c1 = gw2 @ c2) + corr head partials ----
    {
      f32x4 accc[2];
      accc[0] = (f32x4)0.f; accc[1] = (f32x4)0.f;
      #pragma unroll
      for (int kt = 0; kt < 4; ++kt){
        bf16x8 bh = asfrag(*(const uint4*)(sm + RACT + kt*2048       ));
        bf16x8 bl = asfrag(*(const uint4*)(sm + RACT + kt*2048 + 8192));
        bf16x8 a0 = asfrag(*(const uint4*)(sm + RAR + kt*8192      ));
        bf16x8 a1 = asfrag(*(const uint4*)(sm + RAR + kt*8192 + 256));
        accc[0] = MFMA(a0, bl, accc[0]); accc[0] = MFMA(a0, bh, accc[0]);
        accc[1] = MFMA(a1, bl, accc[1]); accc[1] = MFMA(a1, bh, accc[1]);
      }
      float pc0 = 0, pc1 = 0;
      #pragma unroll
      for (int mi = 0; mi < 2; ++mi){
        f32x4 gb1v = *(const f32x4*)(sm + REP + mi*64 + EP_GB1B );
        f32x4 b0v  = *(const f32x4*)(sm + REP + mi*64 + EP_GW1B0);
        f32x4 b1v  = *(const f32x4*)(sm + REP + mi*64 + EP_GW1B1);
        #pragma unroll
        for (int r = 0; r < 4; ++r){
          float z1 = gb1v[r] + ycur0*b0v[r] + ycur1*b1v[r];
          float u  = accc[mi][r] * fsilud(z1);
          pc0 += u * b0v[r];
          pc1 += u * b1v[r];
        }
      }
      pc0 += __shfl_xor(pc0, 16, 64); pc0 += __shfl_xor(pc0, 32, 64);
      pc1 += __shfl_xor(pc1, 16, 64); pc1 += __shfl_xor(pc1, 32, 64);
      if (lane < 16)
        *(float2*)(sm + WPART + 2048) = make_float2(pc0, pc1);
    }
    BAR();                                               // E: corr partials ready

    // ---- S5: Milstein update (redundant per lane) + output ----
    {
      float f0 = fb3r0, f1 = fb3r1, c0 = 0.f, c1 = 0.f;
      #pragma unroll
      for (int w2 = 0; w2 < 4; ++w2){
        float2 a = *(const float2*)(sm + RPART + w2*256       );
        float2 b = *(const float2*)(sm + RPART + w2*256 + 2048);
        f0 += a.x; f1 += a.y; c0 += b.x; c1 += b.y;
      }
      ycur0 += f0*dt + g0*dw0 + c0;
      ycur1 += f1*dt + g1*dw1 + c1;
      if (w < 2 && lane < 16){
        size_t r = (size_t)gp * TLEN + (t + 1);
        if (isbf) ((unsigned*)out)[r] = (unsigned)f2bf(ycur0) | ((unsigned)f2bf(ycur1) << 16);
        else      ((float2*)out)[r]   = make_float2(ycur0, ycur1);
      }
      dwcur = dwnext;
    }
  }
}

extern "C" void kernel_launch(void* const* d_in, const int* in_sizes, int n_in,
                              void* d_out, int out_size, void* d_ws, size_t ws_size,
                              hipStream_t stream)
{
  (void)in_sizes; (void)n_in; (void)out_size; (void)d_ws; (void)ws_size;
  hipFuncSetAttribute((const void*)GeneratorSDE_kernel,
                      hipFuncAttributeMaxDynamicSharedMemorySize, SMEM_BYTES);
  GeneratorSDE_kernel<<<dim3(NPATH / BP), dim3(NTHR), SMEM_BYTES, stream>>>(
      d_in[0], d_in[1], d_in[2],
      d_in[3], d_in[4], d_in[5], d_in[6], d_in[7], d_in[8],
      d_in[9], d_in[10], d_in[11], d_in[12], d_in[13], d_in[14],
      d_out);
}

// Round 7
// 2021.088 us; speedup vs baseline: 1.0616x; 1.0616x over previous
//
#include <hip/hip_runtime.h>
#include <math.h>

#define H      128
#define NPATH  8192
#define TLEN   512
#define BP     32            // paths per block
#define NTHR   512           // 8 waves: (wp 0..3) x (nt 0..1)

typedef short bf16x8 __attribute__((ext_vector_type(8)));
typedef float f32x4  __attribute__((ext_vector_type(4)));

#define MFMA(a,b,c) __builtin_amdgcn_mfma_f32_16x16x32_bf16((a),(b),(c),0,0,0)

// Block-wide barrier draining ONLY LDS (cross-wave dataflow is LDS-only).
#define BAR() asm volatile("s_waitcnt lgkmcnt(0)\n\ts_barrier" ::: "memory")

// ---- LDS byte offsets (weights live in REGISTERS now; LDS is acts+partials) ----
// Activation B buffers: chunk-tiled [c = k>>3][path 0..31] x 16B
#define O_BFH   0                    // h1f hi (reused c2 hi)
#define O_BFL   8192                 // h1f lo (reused c2 lo)
#define O_BGH   16384                // h1g hi
#define O_BGL   24576                // h1g lo
#define O_PF    32768                // f partials [4 wp][32 path] float2
#define O_PRAW  33792
#define O_PCORR 34816
#define O_EP    35840                // epilogue invariants, f32 arrays [128]
#define EP_FB2   0
#define EP_GB2   512
#define EP_W3F0  1024
#define EP_W3F1  1536
#define EP_W3G0  2048
#define EP_W3G1  2560
#define EP_GW1B0 3072
#define EP_GW1B1 3584
#define EP_GB1B  4096
#define O_TS    40448                // ts [512] fp32
#define SMEM_BYTES (O_TS + TLEN*4)   // 42496 B

__device__ __forceinline__ float bf2f(unsigned v){ return __uint_as_float(v << 16); }
__device__ __forceinline__ unsigned short f2bf(float f){
  unsigned u = __float_as_uint(f);
  return (unsigned short)((u + 0x7fffu + ((u >> 16) & 1u)) >> 16);
}
__device__ __forceinline__ float ldany(const void* p, long long i, bool isbf){
  return isbf ? bf2f(((const unsigned short*)p)[i]) : ((const float*)p)[i];
}
__device__ __forceinline__ unsigned short ldbf(const void* p, long long i, bool isbf){
  return isbf ? ((const unsigned short*)p)[i] : f2bf(((const float*)p)[i]);
}
__device__ __forceinline__ float fsig(float x){
  return __builtin_amdgcn_rcpf(1.0f + __expf(-x));
}
__device__ __forceinline__ float fsilu(float x){ return x * fsig(x); }
__device__ __forceinline__ float fsilud(float x){
  float s = fsig(x); return s * (1.0f + x * (1.0f - s));
}
__device__ __forceinline__ float fsoftplus(float x){
  if (x > 15.0f) return x;
  return __logf(1.0f + __expf(x));
}
// packed RTNE f32->2xbf16 (lo16 = a, hi16 = b)  [validated rounds 2-6]
__device__ __forceinline__ unsigned cvtpk(float a, float b){
  unsigned r; asm("v_cvt_pk_bf16_f32 %0, %1, %2" : "=v"(r) : "v"(a), "v"(b)); return r;
}
__device__ __forceinline__ bf16x8 asfrag(uint4 u){
  union { uint4 u; bf16x8 b; } v; v.u = u; return v.b;
}

// NOTE: hipcc treats the 2nd launch-bounds arg as min BLOCKS/CU (CUDA semantics):
// (512,2) capped VGPRs at 128 (2 blocks assumed) and forced R3's spill. LDS keeps
// us at 1 block/CU regardless, so declare 1 and unlock the 256-VGPR budget
// (2 waves/SIMD needs only VGPR<=256).
__global__ __launch_bounds__(NTHR, 1)
void GeneratorSDE_kernel(const void* __restrict__ y0, const void* __restrict__ ts,
                         const void* __restrict__ dW,
                         const void* __restrict__ fw1, const void* __restrict__ fb1,
                         const void* __restrict__ fw2, const void* __restrict__ fb2,
                         const void* __restrict__ fw3, const void* __restrict__ fb3,
                         const void* __restrict__ gw1, const void* __restrict__ gb1,
                         const void* __restrict__ gw2, const void* __restrict__ gb2,
                         const void* __restrict__ gw3, const void* __restrict__ gb3,
                         void* __restrict__ out)
{
  extern __shared__ char sm[];
  const int tid  = threadIdx.x;
  const int lane = tid & 63;
  const int w    = tid >> 6;       // wave 0..7
  const int wp   = w >> 1;         // M-pair index 0..3 (rows 32*wp..32*wp+31)
  const int nt   = w & 1;          // half (paths nt*16..nt*16+15)
  const int m16  = lane & 15;
  const int q    = lane >> 4;      // 0..3
  const int gpb  = blockIdx.x * BP;
  const int p1   = nt*16 + m16;    // this lane's path (block-local)
  const int gp   = gpb + p1;
  const int k8   = wp*32 + q*8;    // S0 k-slice (8 neurons)

  const bool isbf = (((const unsigned*)ts)[1] != 0x3f800000u);

  // ---------- loop-invariant LDS base addresses (bytes) ----------
  const int RACT  = O_BFH + ((q*32 + p1) << 4);
  const int WACT  = O_BFH + (((wp*4 + q)*32 + p1) << 4);
  const int WC2   = O_BFH + (((wp*4 + (q >> 1))*32 + p1) << 4) + ((q & 1) << 3);
  const int RPART = O_PF + (p1 << 3);
  const int WPART = O_PF + ((wp*32 + p1) << 3);
  const int REP   = O_EP + wp*128 + q*16;

  // ---------- MFMA A-fragments in registers (time-invariant weights) ----------
  // A-frag layout (16x16x32): lane holds A[m = lane&15][k = (lane>>4)*8 + j]
  // fwd f : A = fw2^T  -> elem fw2[col][row]  (fw2 is [k_in][n_out] row-major)
  // fwd g : A = gw2^T  -> elem gw2[col][row]
  // bwd   : A = gw2    -> elem gw2[row][col]
  bf16x8 aF[2][4], aG[2][4], aR[2][4];   // [mi][kt] : 96 VGPRs (fits 256 budget)
  #pragma unroll
  for (int mi = 0; mi < 2; ++mi)
    #pragma unroll
    for (int kt = 0; kt < 4; ++kt){
      int row = 32*wp + 16*mi + m16;
      #pragma unroll
      for (int j = 0; j < 8; ++j){
        int col = kt*32 + q*8 + j;
        aF[mi][kt][j] = (short)ldbf(fw2, (long long)col*H + row, isbf);
        aG[mi][kt][j] = (short)ldbf(gw2, (long long)col*H + row, isbf);
        aR[mi][kt][j] = (short)ldbf(gw2, (long long)row*H + col, isbf);
      }
    }

  // epilogue invariants -> LDS (broadcast-read later)
  if (tid < H){
    int e = tid;
    ((float*)(sm + O_EP + EP_FB2))[e]   = ldany(fb2, e, isbf);
    ((float*)(sm + O_EP + EP_GB2))[e]   = ldany(gb2, e, isbf);
    ((float*)(sm + O_EP + EP_W3F0))[e]  = ldany(fw3, 2*e + 0, isbf);
    ((float*)(sm + O_EP + EP_W3F1))[e]  = ldany(fw3, 2*e + 1, isbf);
    ((float*)(sm + O_EP + EP_W3G0))[e]  = ldany(gw3, 2*e + 0, isbf);
    ((float*)(sm + O_EP + EP_W3G1))[e]  = ldany(gw3, 2*e + 1, isbf);
    ((float*)(sm + O_EP + EP_GW1B0))[e] = ldany(gw1, e, isbf);
    ((float*)(sm + O_EP + EP_GW1B1))[e] = ldany(gw1, H + e, isbf);
    ((float*)(sm + O_EP + EP_GB1B))[e]  = ldany(gb1, e, isbf);
  }
  for (int e = tid; e < TLEN; e += NTHR)
    ((float*)(sm + O_TS))[e] = ldany(ts, e, isbf);

  // ---------- register invariants: S0 layer-1 slices ----------
  // spread column folded: y0*w0 + y1*w1 + (y0-y1)*w2 = y0*(w0+w2) + y1*(w1-w2)
  float fw1a[8], fw1b[8], fb1r[8], gw1r0[8], gw1r1[8], gb1r[8];
  #pragma unroll
  for (int kk = 0; kk < 8; ++kk){
    int k = k8 + kk;
    float r0 = ldany(fw1, k, isbf), r1 = ldany(fw1, H + k, isbf), r2 = ldany(fw1, 2*H + k, isbf);
    fw1a[kk]  = r0 + r2;
    fw1b[kk]  = r1 - r2;
    fb1r[kk]  = ldany(fb1, k,     isbf);
    gw1r0[kk] = ldany(gw1, k,     isbf);
    gw1r1[kk] = ldany(gw1, H + k, isbf);
    gb1r[kk]  = ldany(gb1, k,     isbf);
  }
  const float fb3r0 = ldany(fb3, 0, isbf), fb3r1 = ldany(fb3, 1, isbf);
  const float gb3r0 = ldany(gb3, 0, isbf), gb3r1 = ldany(gb3, 1, isbf);

  // ---------- y in registers (redundant across the 16 lanes sharing a path) ----------
  float ycur0 = ldany(y0, (long long)gp*2 + 0, isbf);
  float ycur1 = ldany(y0, (long long)gp*2 + 1, isbf);
  if (w < 2 && lane < 16){                       // one store per path
    size_t r = (size_t)gp * TLEN;
    if (isbf) ((unsigned*)out)[r] = (unsigned)f2bf(ycur0) | ((unsigned)f2bf(ycur1) << 16);
    else      ((float2*)out)[r]   = make_float2(ycur0, ycur1);
  }
  float2 dwcur;
  {
    long long e = (long long)gp * 2;             // t = 0
    if (isbf){ unsigned u = *(const unsigned*)((const unsigned short*)dW + e);
               dwcur = make_float2(bf2f(u & 0xffffu), bf2f(u >> 16)); }
    else       dwcur = *(const float2*)((const float*)dW + e);
  }
  __syncthreads();                               // staging visible (full drain, once)

  const float* TSf = (const float*)(sm + O_TS);

  for (int t = 0; t < TLEN - 1; ++t){
    float dt = TSf[t+1] - TSf[t];
    float sqdt = sqrtf(dt);

    // prefetch next-step dW for this lane's path (stays in flight across BAR()s)
    float2 dwnext;
    {
      int tn = (t + 1 <= TLEN - 2) ? t + 1 : TLEN - 2;
      long long e = ((long long)tn * NPATH + gp) * 2;
      if (isbf){ unsigned u = *(const unsigned*)((const unsigned short*)dW + e);
                 dwnext = make_float2(bf2f(u & 0xffffu), bf2f(u >> 16)); }
      else       dwnext = *(const float2*)((const float*)dW + e);
    }

    // ---- S0: layer 1 (drift + diffusion) for (path p1, 8 k's), split hi/lo ----
    {
      float hf[8], hg[8];
      #pragma unroll
      for (int kk = 0; kk < 8; ++kk){
        hf[kk] = fsilu(fb1r[kk] + ycur0*fw1a[kk]  + ycur1*fw1b[kk]);
        hg[kk] = fsilu(gb1r[kk] + ycur0*gw1r0[kk] + ycur1*gw1r1[kk]);
      }
      unsigned fh[4], fl[4], gh[4], gl[4];
      #pragma unroll
      for (int i = 0; i < 4; ++i){
        fh[i] = cvtpk(hf[2*i], hf[2*i+1]);
        gh[i] = cvtpk(hg[2*i], hg[2*i+1]);
        float f0 = __uint_as_float(fh[i] << 16), f1 = __uint_as_float(fh[i] & 0xffff0000u);
        float g0 = __uint_as_float(gh[i] << 16), g1 = __uint_as_float(gh[i] & 0xffff0000u);
        fl[i] = cvtpk(hf[2*i] - f0, hf[2*i+1] - f1);
        gl[i] = cvtpk(hg[2*i] - g0, hg[2*i+1] - g1);
      }
      *(uint4*)(sm + WACT        ) = make_uint4(fh[0], fh[1], fh[2], fh[3]);
      *(uint4*)(sm + WACT +  8192) = make_uint4(fl[0], fl[1], fl[2], fl[3]);
      *(uint4*)(sm + WACT + 16384) = make_uint4(gh[0], gh[1], gh[2], gh[3]);
      *(uint4*)(sm + WACT + 24576) = make_uint4(gl[0], gl[1], gl[2], gl[3]);
    }
    BAR();                                               // A: acts ready

    // ---- S1: fwd MFMAs (f and g) + head partials ----
    f32x4 accg[2];
    float sgr[8];
    f32x4 w3g0v[2], w3g1v[2];
    {
      f32x4 accf[2];
      accf[0] = (f32x4)0.f; accf[1] = (f32x4)0.f;
      accg[0] = (f32x4)0.f; accg[1] = (f32x4)0.f;
      #pragma unroll
      for (int kt = 0; kt < 4; ++kt){
        bf16x8 bfh = asfrag(*(const uint4*)(sm + RACT + kt*2048        ));
        bf16x8 bfl = asfrag(*(const uint4*)(sm + RACT + kt*2048 +  8192));
        bf16x8 bgh = asfrag(*(const uint4*)(sm + RACT + kt*2048 + 16384));
        bf16x8 bgl = asfrag(*(const uint4*)(sm + RACT + kt*2048 + 24576));
        accf[0] = MFMA(aF[0][kt], bfl, accf[0]); accf[0] = MFMA(aF[0][kt], bfh, accf[0]);
        accf[1] = MFMA(aF[1][kt], bfl, accf[1]); accf[1] = MFMA(aF[1][kt], bfh, accf[1]);
        accg[0] = MFMA(aG[0][kt], bgl, accg[0]); accg[0] = MFMA(aG[0][kt], bgh, accg[0]);
        accg[1] = MFMA(aG[1][kt], bgl, accg[1]); accg[1] = MFMA(aG[1][kt], bgh, accg[1]);
      }
      float pf0 = 0, pf1 = 0, pr0 = 0, pr1 = 0;
      #pragma unroll
      for (int mi = 0; mi < 2; ++mi){
        f32x4 fb2v  = *(const f32x4*)(sm + REP + mi*64 + EP_FB2);
        f32x4 gb2v  = *(const f32x4*)(sm + REP + mi*64 + EP_GB2);
        f32x4 w3f0v = *(const f32x4*)(sm + REP + mi*64 + EP_W3F0);
        f32x4 w3f1v = *(const f32x4*)(sm + REP + mi*64 + EP_W3F1);
        w3g0v[mi] = *(const f32x4*)(sm + REP + mi*64 + EP_W3G0);
        w3g1v[mi] = *(const f32x4*)(sm + REP + mi*64 + EP_W3G1);
        #pragma unroll
        for (int r = 0; r < 4; ++r){
          float vf = fsilu(accf[mi][r] + fb2v[r]);
          pf0 += vf * w3f0v[r];
          pf1 += vf * w3f1v[r];
          float zg = accg[mi][r] + gb2v[r];
          float s  = fsig(zg);
          accg[mi][r] = zg;                    // keep biased z2g for S3
          sgr[mi*4+r] = s;                     // keep sigmoid for silu'
          float vg = zg * s;
          pr0 += vg * w3g0v[mi][r];
          pr1 += vg * w3g1v[mi][r];
        }
      }
      pf0 += __shfl_xor(pf0, 16, 64); pf0 += __shfl_xor(pf0, 32, 64);
      pf1 += __shfl_xor(pf1, 16, 64); pf1 += __shfl_xor(pf1, 32, 64);
      pr0 += __shfl_xor(pr0, 16, 64); pr0 += __shfl_xor(pr0, 32, 64);
      pr1 += __shfl_xor(pr1, 16, 64); pr1 += __shfl_xor(pr1, 32, 64);
      if (lane < 16){
        *(float2*)(sm + WPART       ) = make_float2(pf0, pf1);
        *(float2*)(sm + WPART + 1024) = make_float2(pr0, pr1);
      }
    }
    BAR();                                               // B: partials ready

    // ---- S2': every lane combines raw for ITS path -> g, cr (registers) ----
    float g0, g1, dw0, dw1, cr0, cr1;
    {
      float raw0 = gb3r0, raw1 = gb3r1;
      #pragma unroll
      for (int w2 = 0; w2 < 4; ++w2){
        float2 v = *(const float2*)(sm + RPART + w2*256 + 1024);
        raw0 += v.x; raw1 += v.y;
      }
      dw0 = dwcur.x * sqdt; dw1 = dwcur.y * sqdt;
      float vv0 = 0.5f*(dw0*dw0 - dt), vv1 = 0.5f*(dw1*dw1 - dt);
      float sp0 = fsoftplus(raw0), sp1 = fsoftplus(raw1);
      g0 = fminf(fmaxf(sp0, 1e-4f), 5.0f);
      g1 = fminf(fmaxf(sp1, 1e-4f), 5.0f);
      float m0 = (sp0 > 1e-4f && sp0 < 5.0f) ? 1.0f : 0.0f;
      float m1 = (sp1 > 1e-4f && sp1 < 5.0f) ? 1.0f : 0.0f;
      cr0 = vv0 * (g0 * fsig(raw0) * m0);
      cr1 = vv1 * (g1 * fsig(raw1) * m1);
    }

    // ---- S3: cotangent seed c2 -> BFH/BFL (reuse), silu' from kept sigmoid ----
    #pragma unroll
    for (int mi = 0; mi < 2; ++mi){
      float c2[4];
      #pragma unroll
      for (int r = 0; r < 4; ++r){
        float s = sgr[mi*4+r], z = accg[mi][r];
        float sd = s * (1.0f + z * (1.0f - s));
        c2[r] = (cr0 * w3g0v[mi][r] + cr1 * w3g1v[mi][r]) * sd;
      }
      unsigned h0 = cvtpk(c2[0], c2[1]), h1 = cvtpk(c2[2], c2[3]);
      float a0 = __uint_as_float(h0 << 16), a1 = __uint_as_float(h0 & 0xffff0000u);
      float a2 = __uint_as_float(h1 << 16), a3 = __uint_as_float(h1 & 0xffff0000u);
      unsigned l0 = cvtpk(c2[0] - a0, c2[1] - a1), l1 = cvtpk(c2[2] - a2, c2[3] - a3);
      *(uint2*)(sm + WC2 + mi*1024       ) = make_uint2(h0, h1);
      *(uint2*)(sm + WC2 + mi*1024 + 8192) = make_uint2(l0, l1);
    }
    BAR();                                               // D: c2 ready

    // ---- S4: backward MFMA (c1 = gw2 @ c2) + corr head partials ----
    {
      f32x4 accc[2];
      accc[0] = (f32x4)0.f; accc[1] = (f32x4)0.f;
      #pragma unroll
      for (int kt = 0; kt < 4; ++kt){
        bf16x8 bh = asfrag(*(const uint4*)(sm + RACT + kt*2048       ));
        bf16x8 bl = asfrag(*(const uint4*)(sm + RACT + kt*2048 + 8192));
        accc[0] = MFMA(aR[0][kt], bl, accc[0]); accc[0] = MFMA(aR[0][kt], bh, accc[0]);
        accc[1] = MFMA(aR[1][kt], bl, accc[1]); accc[1] = MFMA(aR[1][kt], bh, accc[1]);
      }
      float pc0 = 0, pc1 = 0;
      #pragma unroll
      for (int mi = 0; mi < 2; ++mi){
        f32x4 gb1v = *(const f32x4*)(sm + REP + mi*64 + EP_GB1B );
        f32x4 b0v  = *(const f32x4*)(sm + REP + mi*64 + EP_GW1B0);
        f32x4 b1v  = *(const f32x4*)(sm + REP + mi*64 + EP_GW1B1);
        #pragma unroll
        for (int r = 0; r < 4; ++r){
          float z1 = gb1v[r] + ycur0*b0v[r] + ycur1*b1v[r];
          float u  = accc[mi][r] * fsilud(z1);
          pc0 += u * b0v[r];
          pc1 += u * b1v[r];
        }
      }
      pc0 += __shfl_xor(pc0, 16, 64); pc0 += __shfl_xor(pc0, 32, 64);
      pc1 += __shfl_xor(pc1, 16, 64); pc1 += __shfl_xor(pc1, 32, 64);
      if (lane < 16)
        *(float2*)(sm + WPART + 2048) = make_float2(pc0, pc1);
    }
    BAR();                                               // E: corr partials ready

    // ---- S5: Milstein update (redundant per lane) + output ----
    {
      float f0 = fb3r0, f1 = fb3r1, c0 = 0.f, c1 = 0.f;
      #pragma unroll
      for (int w2 = 0; w2 < 4; ++w2){
        float2 a = *(const float2*)(sm + RPART + w2*256       );
        float2 b = *(const float2*)(sm + RPART + w2*256 + 2048);
        f0 += a.x; f1 += a.y; c0 += b.x; c1 += b.y;
      }
      ycur0 += f0*dt + g0*dw0 + c0;
      ycur1 += f1*dt + g1*dw1 + c1;
      if (w < 2 && lane < 16){
        size_t r = (size_t)gp * TLEN + (t + 1);
        if (isbf) ((unsigned*)out)[r] = (unsigned)f2bf(ycur0) | ((unsigned)f2bf(ycur1) << 16);
        else      ((float2*)out)[r]   = make_float2(ycur0, ycur1);
      }
      dwcur = dwnext;
    }
  }
}

extern "C" void kernel_launch(void* const* d_in, const int* in_sizes, int n_in,
                              void* d_out, int out_size, void* d_ws, size_t ws_size,
                              hipStream_t stream)
{
  (void)in_sizes; (void)n_in; (void)out_size; (void)d_ws; (void)ws_size;
  hipFuncSetAttribute((const void*)GeneratorSDE_kernel,
                      hipFuncAttributeMaxDynamicSharedMemorySize, SMEM_BYTES);
  GeneratorSDE_kernel<<<dim3(NPATH / BP), dim3(NTHR), SMEM_BYTES, stream>>>(
      d_in[0], d_in[1], d_in[2],
      d_in[3], d_in[4], d_in[5], d_in[6], d_in[7], d_in[8],
      d_in[9], d_in[10], d_in[11], d_in[12], d_in[13], d_in[14],
      d_out);
}